// Round 4
// baseline (88.046 us; speedup 1.0000x reference)
//
#include <hip/hip_runtime.h>
#include <stdint.h>

// Problem constants (from reference)
#define BATCH 1024
#define FEAT  784
#define OUTF  1024
#define OR_T  32
#define AND_T 16
#define NIDX  1569          // 1 + 2*FEAT boolean input columns

typedef unsigned long long u64;
typedef __attribute__((ext_vector_type(2))) u64 u64x2;   // 16B, ds_read_b128

// OR with the lane^32 partner's value (u64, via two 32-bit shfls)
static __device__ __forceinline__ u64 or_shfl_xor32(u64 v) {
    unsigned int lo = __shfl_xor((unsigned int)v, 32);
    unsigned int hi = __shfl_xor((unsigned int)(v >> 32), 32);
    return v | (((u64)hi << 32) | (u64)lo);
}

// ---------------------------------------------------------------------------
// Fused kernel, 128 batch rows per block via u64x2 bit columns.
//
// grid = (8 batch-groups of 128 rows, 32 output-chunks of 32), block = 1024.
// Pack: waves 0-7 pack rows g*128+0..63 into .x, waves 8-15 pack rows
//       +64..127 into .y; __ballot builds each 64-bit column word.
// Eval: thread (o_local=tid&31, tg=tid>>5) evaluates OR-term tg of output
//       ob*32+o_local: 16 random ds_read_b128 gathers ANDed over u64x2.
// Reduce: shfl_xor(32) folds term pairs in-wave; two padded u64 LDS planes
//       (lo/hi rows) hold 16 partials per output; final OR of 16 is
//       2-way-conflict-free; each thread stores 4 output ints (int32 out —
//       reference returns bool, harness reads np.int32).
// ---------------------------------------------------------------------------
__global__ __launch_bounds__(1024) void binlayer(const float* __restrict__ x,
                                                 const int* __restrict__ w,
                                                 int* __restrict__ out) {
    __shared__ u64x2 lbits[1600];          // 25.6 KB bit table
    __shared__ u64 red_lo[16 * 33];        // [wave][output], +1 pad
    __shared__ u64 red_hi[16 * 33];

    const int g    = blockIdx.x;           // batch group of 128 rows
    const int ob   = blockIdx.y;           // output chunk of 32
    const int tid  = threadIdx.x;
    const int lane = tid & 63;
    const int wv   = tid >> 6;             // wave 0..15

    // ---- pack phase -------------------------------------------------------
    const int half = wv >> 3;              // 0: rows +0..63 (.x), 1: +64..127 (.y)
    const int wsub = wv & 7;
    const int cnt   = (wsub < 4) ? 25 : 24;          // 196 float4 chunks / 8 waves
    const int start = wsub * 24 + (wsub < 4 ? wsub : 4);
    const float4* xrow =
        (const float4*)(x + (size_t)(g * 128 + half * 64 + lane) * FEAT);

    for (int i = 0; i < cnt; ++i) {
        const int f4 = start + i;
        const float4 v = xrow[f4];
        const int f = f4 * 4;
        const u64 m0 = __ballot(v.x != 0.0f);
        const u64 m1 = __ballot(v.y != 0.0f);
        const u64 m2 = __ballot(v.z != 0.0f);
        const u64 m3 = __ballot(v.w != 0.0f);
        const u64 mv = (lane == 0) ? m0 : (lane == 1) ? m1 : (lane == 2) ? m2 : m3;
        if (lane < 4) {
            if (half == 0) {
                lbits[1 + f + lane].x   = mv;
                lbits[785 + f + lane].x = ~mv;
            } else {
                lbits[1 + f + lane].y   = mv;
                lbits[785 + f + lane].y = ~mv;
            }
        }
    }
    if (tid == 0) { lbits[0].x = ~0ull; lbits[0].y = ~0ull; }
    __syncthreads();

    // ---- eval phase: one OR-term per thread -------------------------------
    const int o_local = tid & 31;
    const int tg      = tid >> 5;          // term 0..31
    const int o       = ob * 32 + o_local;

    const int4* wq = (const int4*)(w + ((size_t)o * OR_T + tg) * AND_T);

    u64x2 a = {~0ull, ~0ull};
    int zor = 0;                           // OR of the 16 indices (or_mask)
    #pragma unroll
    for (int k = 0; k < 4; ++k) {
        const int4 wi = wq[k];
        zor |= wi.x | wi.y | wi.z | wi.w;
        a &= lbits[wi.x];
        a &= lbits[wi.y];
        a &= lbits[wi.z];
        a &= lbits[wi.w];
    }
    u64 vlo = (zor != 0) ? a.x : 0ull;     // masked-off all-zero term
    u64 vhi = (zor != 0) ? a.y : 0ull;

    // fold the wave's two terms (tg = 2*wv, 2*wv+1) in-register
    vlo = or_shfl_xor32(vlo);
    vhi = or_shfl_xor32(vhi);
    if (lane < 32) {
        red_lo[wv * 33 + o_local] = vlo;
        red_hi[wv * 33 + o_local] = vhi;
    }
    __syncthreads();

    // ---- final OR of 16 partials + store ----------------------------------
    // thread covers output o2, rows rbase..rbase+3 (j = row-plane, wave-uniform)
    const int o2   = tid & 31;
    const int rgrp = tid >> 5;             // 0..31
    const int j    = rgrp >> 4;            // 0: rows 0..63, 1: rows 64..127
    const u64* plane = j ? red_hi : red_lo;

    u64 v = 0;
    #pragma unroll
    for (int k = 0; k < 16; ++k) v |= plane[k * 33 + o2];

    const int rb = (rgrp & 15) * 4;        // bit offset within the plane word
    int* outp = out + (size_t)(g * 128 + j * 64 + rb) * OUTF + ob * 32 + o2;
    #pragma unroll
    for (int i = 0; i < 4; ++i) {
        outp[(size_t)i * OUTF] = (int)((v >> (rb + i)) & 1);
    }
}

extern "C" void kernel_launch(void* const* d_in, const int* in_sizes, int n_in,
                              void* d_out, int out_size, void* d_ws, size_t ws_size,
                              hipStream_t stream) {
    const float* x = (const float*)d_in[0];   // (1024, 784) float32 of 0/1
    const int*   w = (const int*)d_in[1];     // (1024, 32, 16) int32 in [0,1569)
    int* out = (int*)d_out;                   // (1024, 1024) bool -> int32

    binlayer<<<dim3(BATCH / 128, OUTF / 32), 1024, 0, stream>>>(x, w, out);
}

// Round 5
// 71.882 us; speedup vs baseline: 1.2249x; 1.2249x over previous
//
#include <hip/hip_runtime.h>
#include <stdint.h>

// Problem constants (from reference)
#define BATCH 1024
#define FEAT  784
#define OUTF  1024
#define OR_T  32
#define AND_T 16
#define NIDX  1569          // 1 + 2*FEAT boolean input columns
#define BSTRIDE 1600        // padded u64 words per batch-group bit column
#define NGROUP  16          // BATCH / 64

typedef unsigned long long u64;

// ---------------------------------------------------------------------------
// Kernel 1: build bit-packed x_in columns ONCE (x read exactly once).
// bits[g*BSTRIDE + idx] : bit j = x_in[g*64+j][idx]
//   idx 0 -> ones; 1..784 -> x!=0; 785..1568 -> !(x!=0)
// grid (16 groups, 7 f-chunks), one wave each; __ballot builds each column.
// ---------------------------------------------------------------------------
__global__ __launch_bounds__(64) void pack_bits(const float* __restrict__ x,
                                                u64* __restrict__ bits) {
    const int g    = blockIdx.x;
    const int fb   = blockIdx.y;
    const int lane = threadIdx.x;
    const float4* xrow = (const float4*)(x + (size_t)(g * 64 + lane) * FEAT);
    u64* bg = bits + (size_t)g * BSTRIDE;

    for (int i = 0; i < 28; ++i) {          // 7 chunks * 28 * 4 = 784 features
        const int f4 = fb * 28 + i;
        const float4 v = xrow[f4];
        const int f = f4 * 4;
        const u64 m0 = __ballot(v.x != 0.0f);
        const u64 m1 = __ballot(v.y != 0.0f);
        const u64 m2 = __ballot(v.z != 0.0f);
        const u64 m3 = __ballot(v.w != 0.0f);
        const u64 mv = (lane == 0) ? m0 : (lane == 1) ? m1 : (lane == 2) ? m2 : m3;
        if (lane < 4) {
            bg[1 + f + lane]   = mv;
            bg[785 + f + lane] = ~mv;
        }
    }
    if (fb == 0 && lane == 0) bg[0] = ~0ull;
}

// ---------------------------------------------------------------------------
// Kernel 2: evaluate OR-of-ANDs. grid (16 groups, 16 output-chunks),
// block = 1024 (16 waves/CU). Stage the 12.8 KB bit table from ws
// (L2-resident, 2 coalesced u64 loads/thread), then thread (tg, o_local)
// evaluates 2 OR-terms of output ob*64+o_local -> 32 random ds_read_b64
// gathers; OR-reduce 16 partials via LDS; 4 coalesced int stores/thread.
// Output dtype int32 (reference returns bool -> harness reads np.int32).
// ---------------------------------------------------------------------------
__global__ __launch_bounds__(1024) void eval_logic(const int* __restrict__ w,
                                                   const u64* __restrict__ bits,
                                                   int* __restrict__ out) {
    __shared__ u64 lbits[BSTRIDE];
    __shared__ u64 red[1024];

    const int g   = blockIdx.x;
    const int ob  = blockIdx.y;
    const int tid = threadIdx.x;

    // Stage bit table (coalesced; 1600/1024 -> 2 iterations)
    const u64* bg = bits + (size_t)g * BSTRIDE;
    for (int i = tid; i < BSTRIDE; i += 1024) lbits[i] = bg[i];
    __syncthreads();

    const int o_local = tid & 63;
    const int tg      = tid >> 6;         // term-group 0..15
    const int o       = ob * 64 + o_local;

    // terms tg*2, tg*2+1 of output o
    const int4* wq = (const int4*)(w + ((size_t)o * OR_T + tg * 2) * AND_T);

    u64 orv = 0;
    #pragma unroll
    for (int tt = 0; tt < 2; ++tt) {
        u64 a = ~0ull;
        int zor = 0;                      // OR of the 16 indices (or_mask)
        #pragma unroll
        for (int k = 0; k < 4; ++k) {
            const int4 wi = wq[tt * 4 + k];
            zor |= wi.x | wi.y | wi.z | wi.w;
            a &= lbits[wi.x];
            a &= lbits[wi.y];
            a &= lbits[wi.z];
            a &= lbits[wi.w];
        }
        if (zor != 0) orv |= a;           // all-zero term is masked off
    }

    red[tid] = orv;
    __syncthreads();

    // OR across the 16 term-groups
    u64 full = 0;
    #pragma unroll
    for (int j = 0; j < 16; ++j) full |= red[o_local + j * 64];

    // each thread writes 4 batch rows; o_local in lane bits -> coalesced
    int* outg = out + (size_t)(g * 64) * OUTF + (size_t)ob * 64;
    #pragma unroll
    for (int jj = 0; jj < 4; ++jj) {
        const int j = tg * 4 + jj;
        outg[(size_t)j * OUTF + o_local] = (int)((full >> j) & 1);
    }
}

// ---------------------------------------------------------------------------
// Fallback: fully fused (R3 structure) if ws is too small. Same math.
// ---------------------------------------------------------------------------
__global__ __launch_bounds__(1024) void binlayer_fused(const float* __restrict__ x,
                                                       const int* __restrict__ w,
                                                       int* __restrict__ out) {
    __shared__ u64 lbits[BSTRIDE];
    __shared__ u64 red[1024];

    const int g    = blockIdx.x;
    const int ob   = blockIdx.y;
    const int tid  = threadIdx.x;
    const int lane = tid & 63;
    const int wv   = tid >> 6;

    const int start = wv * 12 + (wv < 4 ? wv : 4);
    const int cnt   = (wv < 4) ? 13 : 12;
    const float4* xrow = (const float4*)(x + (size_t)(g * 64 + lane) * FEAT);
    for (int i = 0; i < cnt; ++i) {
        const int f4 = start + i;
        const float4 v = xrow[f4];
        const int f = f4 * 4;
        const u64 m0 = __ballot(v.x != 0.0f);
        const u64 m1 = __ballot(v.y != 0.0f);
        const u64 m2 = __ballot(v.z != 0.0f);
        const u64 m3 = __ballot(v.w != 0.0f);
        const u64 mv = (lane == 0) ? m0 : (lane == 1) ? m1 : (lane == 2) ? m2 : m3;
        if (lane < 4) {
            lbits[1 + f + lane]   = mv;
            lbits[785 + f + lane] = ~mv;
        }
    }
    if (tid == 0) lbits[0] = ~0ull;
    __syncthreads();

    const int o_local = tid & 63;
    const int tg      = tid >> 6;
    const int o       = ob * 64 + o_local;
    const int4* wq = (const int4*)(w + ((size_t)o * OR_T + tg * 2) * AND_T);

    u64 orv = 0;
    #pragma unroll
    for (int tt = 0; tt < 2; ++tt) {
        u64 a = ~0ull;
        int zor = 0;
        #pragma unroll
        for (int k = 0; k < 4; ++k) {
            const int4 wi = wq[tt * 4 + k];
            zor |= wi.x | wi.y | wi.z | wi.w;
            a &= lbits[wi.x];
            a &= lbits[wi.y];
            a &= lbits[wi.z];
            a &= lbits[wi.w];
        }
        if (zor != 0) orv |= a;
    }

    red[tid] = orv;
    __syncthreads();

    u64 full = 0;
    #pragma unroll
    for (int j = 0; j < 16; ++j) full |= red[o_local + j * 64];

    int* outg = out + (size_t)(g * 64) * OUTF + (size_t)ob * 64;
    #pragma unroll
    for (int jj = 0; jj < 4; ++jj) {
        const int j = tg * 4 + jj;
        outg[(size_t)j * OUTF + o_local] = (int)((full >> j) & 1);
    }
}

extern "C" void kernel_launch(void* const* d_in, const int* in_sizes, int n_in,
                              void* d_out, int out_size, void* d_ws, size_t ws_size,
                              hipStream_t stream) {
    const float* x = (const float*)d_in[0];   // (1024, 784) float32 of 0/1
    const int*   w = (const int*)d_in[1];     // (1024, 32, 16) int32 in [0,1569)
    int* out = (int*)d_out;                   // (1024, 1024) bool -> int32

    const size_t need = (size_t)NGROUP * BSTRIDE * sizeof(u64);   // 204,800 B
    if (ws_size >= need) {
        u64* bits = (u64*)d_ws;
        pack_bits<<<dim3(NGROUP, 7), 64, 0, stream>>>(x, bits);
        eval_logic<<<dim3(NGROUP, OUTF / 64), 1024, 0, stream>>>(w, bits, out);
    } else {
        binlayer_fused<<<dim3(NGROUP, OUTF / 64), 1024, 0, stream>>>(x, w, out);
    }
}

// Round 6
// 66.127 us; speedup vs baseline: 1.3315x; 1.0870x over previous
//
#include <hip/hip_runtime.h>
#include <stdint.h>

// Problem constants (from reference)
#define BATCH 1024
#define FEAT  784
#define OUTF  1024
#define OR_T  32
#define AND_T 16
#define NIDX  1569          // 1 + 2*FEAT boolean input columns
#define BSTRIDE 1600        // padded u64 words per batch-group bit column
#define NGROUP  16          // BATCH / 64
#define TKDIM   512         // OR_T * AND_T flattened (term,k) extent

// ws layout
#define BITS_BYTES (NGROUP * BSTRIDE * 8)     // 204,800
#define WT_OFF     208896                     // 4 KB-aligned
#define WS_NEED    (WT_OFF + (size_t)TKDIM * OUTF * 4)   // ~2.3 MB

#define NB_PACK 448                           // 16 groups x 28 f-slices
#define NB_TR   128                           // (1024/64) x (512/64)

typedef unsigned long long u64;

// ---------------------------------------------------------------------------
// Prep kernel (64-thread blocks):
//  blocks [0,448): pack bit columns. block (g, fb) handles 7 float4 chunks;
//    lane = batch row; __ballot builds each 64-bit column word.
//    bits[g*BSTRIDE + idx]: idx 0 -> ones; 1..784 -> x!=0; 785.. -> !(x!=0).
//  blocks [448,576): transpose w (1024x512 int) into w_t[tk*1024 + o] via a
//    64x64 LDS tile so eval's weight reads are coalesced along o.
// ---------------------------------------------------------------------------
__global__ __launch_bounds__(64) void prep(const float* __restrict__ x,
                                           const int* __restrict__ w,
                                           u64* __restrict__ bits,
                                           int* __restrict__ wt) {
    __shared__ int t2[64 * 65];
    const int b   = blockIdx.x;
    const int tid = threadIdx.x;

    if (b < NB_PACK) {
        const int g  = b / 28;
        const int fb = b % 28;
        const float4* xrow = (const float4*)(x + (size_t)(g * 64 + tid) * FEAT);
        u64* bg = bits + (size_t)g * BSTRIDE;

        #pragma unroll
        for (int i = 0; i < 7; ++i) {       // 28 slices * 7 * 4 = 784 features
            const int f4 = fb * 7 + i;
            const float4 v = xrow[f4];
            const int f = f4 * 4;
            const u64 m0 = __ballot(v.x != 0.0f);
            const u64 m1 = __ballot(v.y != 0.0f);
            const u64 m2 = __ballot(v.z != 0.0f);
            const u64 m3 = __ballot(v.w != 0.0f);
            const u64 mv = (tid == 0) ? m0 : (tid == 1) ? m1 : (tid == 2) ? m2 : m3;
            if (tid < 4) {
                bg[1 + f + tid]   = mv;
                bg[785 + f + tid] = ~mv;
            }
        }
        if (fb == 0 && tid == 0) bg[0] = ~0ull;
    } else {
        const int b2     = b - NB_PACK;
        const int o_base  = (b2 & 15) * 64;
        const int tk_base = (b2 >> 4) * 64;

        #pragma unroll
        for (int i = 0; i < 16; ++i) {      // load 64(o) x 64(tk) tile
            const int idx = i * 64 + tid;
            const int r = idx >> 4;         // o row 0..63
            const int q = idx & 15;         // tk int4 index
            const int4 v = *(const int4*)(w + (size_t)(o_base + r) * TKDIM
                                            + tk_base + q * 4);
            t2[(q * 4 + 0) * 65 + r] = v.x;
            t2[(q * 4 + 1) * 65 + r] = v.y;
            t2[(q * 4 + 2) * 65 + r] = v.z;
            t2[(q * 4 + 3) * 65 + r] = v.w;
        }
        __syncthreads();
        #pragma unroll
        for (int i = 0; i < 16; ++i) {      // store transposed, coalesced
            const int idx = i * 64 + tid;
            const int rr = idx >> 4;        // tk row 0..63
            const int qq = idx & 15;        // o int4 index
            int4 o4;
            o4.x = t2[rr * 65 + qq * 4 + 0];
            o4.y = t2[rr * 65 + qq * 4 + 1];
            o4.z = t2[rr * 65 + qq * 4 + 2];
            o4.w = t2[rr * 65 + qq * 4 + 3];
            *(int4*)(wt + (size_t)(tk_base + rr) * OUTF + o_base + qq * 4) = o4;
        }
    }
}

// ---------------------------------------------------------------------------
// Eval kernel: grid (16 groups, 16 output-chunks), block 1024 (16 waves/CU).
// Stage the 12.8 KB bit table; thread (tg, o_local) evaluates 2 OR-terms of
// output ob*64+o_local. Weight reads are coalesced dwords from w_t (lanes =
// consecutive o). 32 random ds_read_b64 gathers per thread; LDS OR-reduce;
// 4 coalesced int32 stores (reference returns bool -> harness reads int32).
// ---------------------------------------------------------------------------
__global__ __launch_bounds__(1024) void eval_logic(const int* __restrict__ wt,
                                                   const u64* __restrict__ bits,
                                                   int* __restrict__ out) {
    __shared__ u64 lbits[BSTRIDE];
    __shared__ u64 red[1024];

    const int g   = blockIdx.x;
    const int ob  = blockIdx.y;
    const int tid = threadIdx.x;

    const u64* bg = bits + (size_t)g * BSTRIDE;
    for (int i = tid; i < BSTRIDE; i += 1024) lbits[i] = bg[i];
    __syncthreads();

    const int o_local = tid & 63;
    const int tg      = tid >> 6;          // term-group 0..15
    const int o       = ob * 64 + o_local;

    u64 orv = 0;
    #pragma unroll
    for (int tt = 0; tt < 2; ++tt) {
        const int term = tg * 2 + tt;
        const int* wcol = wt + (size_t)(term * AND_T) * OUTF + o;
        u64 a = ~0ull;
        int zor = 0;                        // OR of the 16 indices (or_mask)
        #pragma unroll
        for (int k = 0; k < 16; ++k) {
            const int idx = wcol[(size_t)k * OUTF];
            zor |= idx;
            a &= lbits[idx];
        }
        if (zor != 0) orv |= a;             // all-zero term is masked off
    }

    red[tid] = orv;
    __syncthreads();

    u64 full = 0;
    #pragma unroll
    for (int j = 0; j < 16; ++j) full |= red[o_local + j * 64];

    int* outg = out + (size_t)(g * 64) * OUTF + (size_t)ob * 64;
    #pragma unroll
    for (int jj = 0; jj < 4; ++jj) {
        const int j = tg * 4 + jj;
        outg[(size_t)j * OUTF + o_local] = (int)((full >> j) & 1);
    }
}

// ---------------------------------------------------------------------------
// Fallback: fully fused (R5 structure) if ws is too small. Same math.
// ---------------------------------------------------------------------------
__global__ __launch_bounds__(1024) void binlayer_fused(const float* __restrict__ x,
                                                       const int* __restrict__ w,
                                                       int* __restrict__ out) {
    __shared__ u64 lbits[BSTRIDE];
    __shared__ u64 red[1024];

    const int g    = blockIdx.x;
    const int ob   = blockIdx.y;
    const int tid  = threadIdx.x;
    const int lane = tid & 63;
    const int wv   = tid >> 6;

    const int start = wv * 12 + (wv < 4 ? wv : 4);
    const int cnt   = (wv < 4) ? 13 : 12;
    const float4* xrow = (const float4*)(x + (size_t)(g * 64 + lane) * FEAT);
    for (int i = 0; i < cnt; ++i) {
        const int f4 = start + i;
        const float4 v = xrow[f4];
        const int f = f4 * 4;
        const u64 m0 = __ballot(v.x != 0.0f);
        const u64 m1 = __ballot(v.y != 0.0f);
        const u64 m2 = __ballot(v.z != 0.0f);
        const u64 m3 = __ballot(v.w != 0.0f);
        const u64 mv = (lane == 0) ? m0 : (lane == 1) ? m1 : (lane == 2) ? m2 : m3;
        if (lane < 4) {
            lbits[1 + f + lane]   = mv;
            lbits[785 + f + lane] = ~mv;
        }
    }
    if (tid == 0) lbits[0] = ~0ull;
    __syncthreads();

    const int o_local = tid & 63;
    const int tg      = tid >> 6;
    const int o       = ob * 64 + o_local;
    const int4* wq = (const int4*)(w + ((size_t)o * OR_T + tg * 2) * AND_T);

    u64 orv = 0;
    #pragma unroll
    for (int tt = 0; tt < 2; ++tt) {
        u64 a = ~0ull;
        int zor = 0;
        #pragma unroll
        for (int k = 0; k < 4; ++k) {
            const int4 wi = wq[tt * 4 + k];
            zor |= wi.x | wi.y | wi.z | wi.w;
            a &= lbits[wi.x];
            a &= lbits[wi.y];
            a &= lbits[wi.z];
            a &= lbits[wi.w];
        }
        if (zor != 0) orv |= a;
    }

    red[tid] = orv;
    __syncthreads();

    u64 full = 0;
    #pragma unroll
    for (int j = 0; j < 16; ++j) full |= red[o_local + j * 64];

    int* outg = out + (size_t)(g * 64) * OUTF + (size_t)ob * 64;
    #pragma unroll
    for (int jj = 0; jj < 4; ++jj) {
        const int j = tg * 4 + jj;
        outg[(size_t)j * OUTF + o_local] = (int)((full >> j) & 1);
    }
}

extern "C" void kernel_launch(void* const* d_in, const int* in_sizes, int n_in,
                              void* d_out, int out_size, void* d_ws, size_t ws_size,
                              hipStream_t stream) {
    const float* x = (const float*)d_in[0];   // (1024, 784) float32 of 0/1
    const int*   w = (const int*)d_in[1];     // (1024, 32, 16) int32 in [0,1569)
    int* out = (int*)d_out;                   // (1024, 1024) bool -> int32

    if (ws_size >= WS_NEED) {
        u64* bits = (u64*)d_ws;
        int* wt   = (int*)((char*)d_ws + WT_OFF);
        prep<<<NB_PACK + NB_TR, 64, 0, stream>>>(x, w, bits, wt);
        eval_logic<<<dim3(NGROUP, OUTF / 64), 1024, 0, stream>>>(wt, bits, out);
    } else {
        binlayer_fused<<<dim3(NGROUP, OUTF / 64), 1024, 0, stream>>>(x, w, out);
    }
}

// Round 7
// 63.857 us; speedup vs baseline: 1.3788x; 1.0355x over previous
//
#include <hip/hip_runtime.h>
#include <stdint.h>

// Problem constants (from reference)
#define BATCH 1024
#define FEAT  784
#define OUTF  1024
#define OR_T  32
#define AND_T 16
#define NIDX  1569          // 1 + 2*FEAT boolean input columns
#define BSTRIDE 1600        // padded u64 words per batch-group bit column
#define NGROUP  16          // BATCH / 64
#define TKDIM   512         // OR_T * AND_T flattened (term,k) extent

// ws layout
#define BITS_BYTES (NGROUP * BSTRIDE * 8)     // 204,800
#define WT_OFF     208896                     // 4 KB-aligned
#define WS_NEED    (WT_OFF + (size_t)TKDIM * OUTF * 4)   // ~2.3 MB

#define NB_PACK 448                           // 16 groups x 28 f-slices
#define NB_TR   128                           // (1024/64) x (512/64)

typedef unsigned long long u64;
typedef __attribute__((ext_vector_type(2))) u64 u64x2;   // 16B

// ---------------------------------------------------------------------------
// Prep kernel (64-thread blocks):
//  blocks [0,448): pack bit columns. block (g, fb) handles 7 float4 chunks;
//    lane = batch row; __ballot builds each 64-bit column word.
//    bits[g*BSTRIDE + idx]: idx 0 -> ones; 1..784 -> x!=0; 785.. -> !(x!=0).
//  blocks [448,576): transpose w (1024x512 int) into w_t[tk*1024 + o] via a
//    64x64 LDS tile so eval's weight reads are coalesced along o.
// ---------------------------------------------------------------------------
__global__ __launch_bounds__(64) void prep(const float* __restrict__ x,
                                           const int* __restrict__ w,
                                           u64* __restrict__ bits,
                                           int* __restrict__ wt) {
    __shared__ int t2[64 * 65];
    const int b   = blockIdx.x;
    const int tid = threadIdx.x;

    if (b < NB_PACK) {
        const int g  = b / 28;
        const int fb = b % 28;
        const float4* xrow = (const float4*)(x + (size_t)(g * 64 + tid) * FEAT);
        u64* bg = bits + (size_t)g * BSTRIDE;

        #pragma unroll
        for (int i = 0; i < 7; ++i) {       // 28 slices * 7 * 4 = 784 features
            const int f4 = fb * 7 + i;
            const float4 v = xrow[f4];
            const int f = f4 * 4;
            const u64 m0 = __ballot(v.x != 0.0f);
            const u64 m1 = __ballot(v.y != 0.0f);
            const u64 m2 = __ballot(v.z != 0.0f);
            const u64 m3 = __ballot(v.w != 0.0f);
            const u64 mv = (tid == 0) ? m0 : (tid == 1) ? m1 : (tid == 2) ? m2 : m3;
            if (tid < 4) {
                bg[1 + f + tid]   = mv;
                bg[785 + f + tid] = ~mv;
            }
        }
        if (fb == 0 && tid == 0) bg[0] = ~0ull;
    } else {
        const int b2     = b - NB_PACK;
        const int o_base  = (b2 & 15) * 64;
        const int tk_base = (b2 >> 4) * 64;

        #pragma unroll
        for (int i = 0; i < 16; ++i) {      // load 64(o) x 64(tk) tile
            const int idx = i * 64 + tid;
            const int r = idx >> 4;         // o row 0..63
            const int q = idx & 15;         // tk int4 index
            const int4 v = *(const int4*)(w + (size_t)(o_base + r) * TKDIM
                                            + tk_base + q * 4);
            t2[(q * 4 + 0) * 65 + r] = v.x;
            t2[(q * 4 + 1) * 65 + r] = v.y;
            t2[(q * 4 + 2) * 65 + r] = v.z;
            t2[(q * 4 + 3) * 65 + r] = v.w;
        }
        __syncthreads();
        #pragma unroll
        for (int i = 0; i < 16; ++i) {      // store transposed, coalesced
            const int idx = i * 64 + tid;
            const int rr = idx >> 4;        // tk row 0..63
            const int qq = idx & 15;        // o int4 index
            int4 o4;
            o4.x = t2[rr * 65 + qq * 4 + 0];
            o4.y = t2[rr * 65 + qq * 4 + 1];
            o4.z = t2[rr * 65 + qq * 4 + 2];
            o4.w = t2[rr * 65 + qq * 4 + 3];
            *(int4*)(wt + (size_t)(tk_base + rr) * OUTF + o_base + qq * 4) = o4;
        }
    }
}

// ---------------------------------------------------------------------------
// Eval kernel: 1D grid of 256 blocks, XCD-swizzled decode so the 32 blocks
// resident on one XCD share only 2 output-chunks -> their 2x128 KB w_t
// slices stay L2-hot. Block (g, ob): stage the 12.8 KB bit table (b128
// copies); thread (tg, o_local) evaluates 2 OR-terms of output ob*64+o_local
// with coalesced w_t dword reads + 32 random ds_read_b64 gathers; LDS
// OR-reduce; 4 coalesced int32 stores (reference bool -> harness int32).
// ---------------------------------------------------------------------------
__global__ __launch_bounds__(1024) void eval_logic(const int* __restrict__ wt,
                                                   const u64* __restrict__ bits,
                                                   int* __restrict__ out) {
    __shared__ u64 lbits[BSTRIDE];
    __shared__ u64 red[1024];

    // XCD swizzle: bid%8 = XCD slot; each XCD sees ob in {xcd, xcd+8} only.
    const int bid = blockIdx.x;
    const int xcd = bid & 7;
    const int s   = bid >> 3;              // 0..31
    const int ob  = xcd + 8 * (s & 1);
    const int g   = s >> 1;
    const int tid = threadIdx.x;

    // Stage bit table: 800 x 16B, one b128 per thread for tid<800.
    const u64* bg = bits + (size_t)g * BSTRIDE;
    if (tid < BSTRIDE / 2) {
        ((u64x2*)lbits)[tid] = ((const u64x2*)bg)[tid];
    }
    __syncthreads();

    const int o_local = tid & 63;
    const int tg      = tid >> 6;          // term-group 0..15
    const int o       = ob * 64 + o_local;

    u64 orv = 0;
    #pragma unroll
    for (int tt = 0; tt < 2; ++tt) {
        const int term = tg * 2 + tt;
        const int* wcol = wt + (size_t)(term * AND_T) * OUTF + o;
        u64 a = ~0ull;
        int zor = 0;                        // OR of the 16 indices (or_mask)
        #pragma unroll
        for (int k = 0; k < 16; ++k) {
            const int idx = wcol[(size_t)k * OUTF];
            zor |= idx;
            a &= lbits[idx];
        }
        if (zor != 0) orv |= a;             // all-zero term is masked off
    }

    red[tid] = orv;
    __syncthreads();

    u64 full = 0;
    #pragma unroll
    for (int j = 0; j < 16; ++j) full |= red[o_local + j * 64];

    int* outg = out + (size_t)(g * 64) * OUTF + (size_t)ob * 64;
    #pragma unroll
    for (int jj = 0; jj < 4; ++jj) {
        const int j = tg * 4 + jj;
        outg[(size_t)j * OUTF + o_local] = (int)((full >> j) & 1);
    }
}

// ---------------------------------------------------------------------------
// Fallback: fully fused if ws is too small. Same math.
// ---------------------------------------------------------------------------
__global__ __launch_bounds__(1024) void binlayer_fused(const float* __restrict__ x,
                                                       const int* __restrict__ w,
                                                       int* __restrict__ out) {
    __shared__ u64 lbits[BSTRIDE];
    __shared__ u64 red[1024];

    const int g    = blockIdx.x;
    const int ob   = blockIdx.y;
    const int tid  = threadIdx.x;
    const int lane = tid & 63;
    const int wv   = tid >> 6;

    const int start = wv * 12 + (wv < 4 ? wv : 4);
    const int cnt   = (wv < 4) ? 13 : 12;
    const float4* xrow = (const float4*)(x + (size_t)(g * 64 + lane) * FEAT);
    for (int i = 0; i < cnt; ++i) {
        const int f4 = start + i;
        const float4 v = xrow[f4];
        const int f = f4 * 4;
        const u64 m0 = __ballot(v.x != 0.0f);
        const u64 m1 = __ballot(v.y != 0.0f);
        const u64 m2 = __ballot(v.z != 0.0f);
        const u64 m3 = __ballot(v.w != 0.0f);
        const u64 mv = (lane == 0) ? m0 : (lane == 1) ? m1 : (lane == 2) ? m2 : m3;
        if (lane < 4) {
            lbits[1 + f + lane]   = mv;
            lbits[785 + f + lane] = ~mv;
        }
    }
    if (tid == 0) lbits[0] = ~0ull;
    __syncthreads();

    const int o_local = tid & 63;
    const int tg      = tid >> 6;
    const int o       = ob * 64 + o_local;
    const int4* wq = (const int4*)(w + ((size_t)o * OR_T + tg * 2) * AND_T);

    u64 orv = 0;
    #pragma unroll
    for (int tt = 0; tt < 2; ++tt) {
        u64 a = ~0ull;
        int zor = 0;
        #pragma unroll
        for (int k = 0; k < 4; ++k) {
            const int4 wi = wq[tt * 4 + k];
            zor |= wi.x | wi.y | wi.z | wi.w;
            a &= lbits[wi.x];
            a &= lbits[wi.y];
            a &= lbits[wi.z];
            a &= lbits[wi.w];
        }
        if (zor != 0) orv |= a;
    }

    red[tid] = orv;
    __syncthreads();

    u64 full = 0;
    #pragma unroll
    for (int j = 0; j < 16; ++j) full |= red[o_local + j * 64];

    int* outg = out + (size_t)(g * 64) * OUTF + (size_t)ob * 64;
    #pragma unroll
    for (int jj = 0; jj < 4; ++jj) {
        const int j = tg * 4 + jj;
        outg[(size_t)j * OUTF + o_local] = (int)((full >> j) & 1);
    }
}

extern "C" void kernel_launch(void* const* d_in, const int* in_sizes, int n_in,
                              void* d_out, int out_size, void* d_ws, size_t ws_size,
                              hipStream_t stream) {
    const float* x = (const float*)d_in[0];   // (1024, 784) float32 of 0/1
    const int*   w = (const int*)d_in[1];     // (1024, 32, 16) int32 in [0,1569)
    int* out = (int*)d_out;                   // (1024, 1024) bool -> int32

    if (ws_size >= WS_NEED) {
        u64* bits = (u64*)d_ws;
        int* wt   = (int*)((char*)d_ws + WT_OFF);
        prep<<<NB_PACK + NB_TR, 64, 0, stream>>>(x, w, bits, wt);
        eval_logic<<<NGROUP * (OUTF / 64), 1024, 0, stream>>>(wt, bits, out);
    } else {
        binlayer_fused<<<dim3(NGROUP, OUTF / 64), 1024, 0, stream>>>(x, w, out);
    }
}